// Round 3
// baseline (1681.672 us; speedup 1.0000x reference)
//
#include <hip/hip_runtime.h>
#include <hip/hip_bf16.h>

// GAT residual block: N=50000 nodes, IN=128, H=4 heads, C=32 (H*C=128), E=800000 edges.
// Inputs (all fp32 except edge_index int32): x, edge_index, W, att_src, att_dst, bias, skip_W, skip_b
// Output: FLOAT32 [N,128]  (reference returns f32; harness threshold analysis confirms no bf16)
//
//  K1 gat_gemm:   xp = x@W^T (store), a_src/a_dst logits (store), agg = x@skip_W^T + skip_b + bias
//  memset denom=0
//  K2 gat_denom:  per edge: e=leaky(a_src[s]+a_dst[d]); atomicAdd(denom[d,h], exp(e))
//  K3 gat_scatter: per (edge, 32 lanes): alpha = exp(e)/(denom[d,h]+1e-16); atomicAdd agg[d] += alpha*xp[s]
//  K4 gat_elu:    out = elu(agg)  [f32]
// Segment-max is skipped (softmax shift-invariance; |e| <~ 6 so exp() is fp32-safe).

#define NN 50000
#define EE 800000
#define FD 128
#define NEG_SLOPE 0.2f

#define TN 16      // nodes per block in GEMM kernel
#define WPAD 132   // padded LDS row stride (floats)

__global__ __launch_bounds__(256) void gat_gemm_kernel(
    const float* __restrict__ x, const float* __restrict__ W,
    const float* __restrict__ skip_W, const float* __restrict__ att_src,
    const float* __restrict__ att_dst, const float* __restrict__ bias,
    const float* __restrict__ skip_b,
    float* __restrict__ xp, float* __restrict__ a_src, float* __restrict__ a_dst,
    float* __restrict__ agg)
{
    __shared__ float xs[TN][FD];     // 8 KB
    __shared__ float Ws[FD][WPAD];   // 66 KB
    const int tid = threadIdx.x;
    const int bn = blockIdx.x * TN;

    // stage x tile
    for (int i = tid; i < TN * (FD / 4); i += 256) {
        int n = i >> 5;              // FD/4 == 32
        int k4 = (i & 31) << 2;
        float4 v = make_float4(0.f, 0.f, 0.f, 0.f);
        int gn = bn + n;
        if (gn < NN) v = *reinterpret_cast<const float4*>(x + (size_t)gn * FD + k4);
        *reinterpret_cast<float4*>(&xs[n][k4]) = v;
    }
    // stage W
    for (int i = tid; i < FD * (FD / 4); i += 256) {
        int j = i >> 5;
        int k4 = (i & 31) << 2;
        *reinterpret_cast<float4*>(&Ws[j][k4]) =
            *reinterpret_cast<const float4*>(W + j * FD + k4);
    }
    __syncthreads();

    const int jg = tid & 31;
    const int ng = tid >> 5;
    const int j0 = jg << 2;      // 4 consecutive output features
    const int n0 = ng << 1;      // 2 nodes per thread
    const int h  = jg >> 3;      // head of this j-quad

    float acc[2][4];
    #pragma unroll
    for (int a = 0; a < 2; ++a)
        #pragma unroll
        for (int b = 0; b < 4; ++b) acc[a][b] = 0.f;

    #pragma unroll 4
    for (int k = 0; k < FD; k += 4) {
        float4 xv0 = *reinterpret_cast<const float4*>(&xs[n0][k]);
        float4 xv1 = *reinterpret_cast<const float4*>(&xs[n0 + 1][k]);
        #pragma unroll
        for (int jj = 0; jj < 4; ++jj) {
            float4 wv = *reinterpret_cast<const float4*>(&Ws[j0 + jj][k]);
            acc[0][jj] += xv0.x * wv.x + xv0.y * wv.y + xv0.z * wv.z + xv0.w * wv.w;
            acc[1][jj] += xv1.x * wv.x + xv1.y * wv.y + xv1.z * wv.z + xv1.w * wv.w;
        }
    }

    // store xp and per-node attention logits
    float4 atts = *reinterpret_cast<const float4*>(att_src + j0);
    float4 attd = *reinterpret_cast<const float4*>(att_dst + j0);
    #pragma unroll
    for (int nn = 0; nn < 2; ++nn) {
        int gn = bn + n0 + nn;
        if (gn < NN)
            *reinterpret_cast<float4*>(xp + (size_t)gn * FD + j0) =
                make_float4(acc[nn][0], acc[nn][1], acc[nn][2], acc[nn][3]);
        float ps = acc[nn][0]*atts.x + acc[nn][1]*atts.y + acc[nn][2]*atts.z + acc[nn][3]*atts.w;
        float pd = acc[nn][0]*attd.x + acc[nn][1]*attd.y + acc[nn][2]*attd.z + acc[nn][3]*attd.w;
        // sum over the 8 lanes (same ng, same head) holding this head's 32 channels
        #pragma unroll
        for (int m = 1; m < 8; m <<= 1) {
            ps += __shfl_xor(ps, m, 64);
            pd += __shfl_xor(pd, m, 64);
        }
        if ((jg & 7) == 0 && gn < NN) {
            a_src[gn * 4 + h] = ps;
            a_dst[gn * 4 + h] = pd;
        }
    }

    // phase 2: skip GEMM into agg (reload LDS with skip_W)
    __syncthreads();
    for (int i = tid; i < FD * (FD / 4); i += 256) {
        int j = i >> 5;
        int k4 = (i & 31) << 2;
        *reinterpret_cast<float4*>(&Ws[j][k4]) =
            *reinterpret_cast<const float4*>(skip_W + j * FD + k4);
    }
    __syncthreads();

    float acc2[2][4];
    #pragma unroll
    for (int a = 0; a < 2; ++a)
        #pragma unroll
        for (int b = 0; b < 4; ++b) acc2[a][b] = 0.f;

    #pragma unroll 4
    for (int k = 0; k < FD; k += 4) {
        float4 xv0 = *reinterpret_cast<const float4*>(&xs[n0][k]);
        float4 xv1 = *reinterpret_cast<const float4*>(&xs[n0 + 1][k]);
        #pragma unroll
        for (int jj = 0; jj < 4; ++jj) {
            float4 wv = *reinterpret_cast<const float4*>(&Ws[j0 + jj][k]);
            acc2[0][jj] += xv0.x * wv.x + xv0.y * wv.y + xv0.z * wv.z + xv0.w * wv.w;
            acc2[1][jj] += xv1.x * wv.x + xv1.y * wv.y + xv1.z * wv.z + xv1.w * wv.w;
        }
    }

    float4 sb = *reinterpret_cast<const float4*>(skip_b + j0);
    float4 bb = *reinterpret_cast<const float4*>(bias + j0);
    #pragma unroll
    for (int nn = 0; nn < 2; ++nn) {
        int gn = bn + n0 + nn;
        if (gn < NN)
            *reinterpret_cast<float4*>(agg + (size_t)gn * FD + j0) =
                make_float4(acc2[nn][0] + sb.x + bb.x, acc2[nn][1] + sb.y + bb.y,
                            acc2[nn][2] + sb.z + bb.z, acc2[nn][3] + sb.w + bb.w);
    }
}

__global__ __launch_bounds__(256) void gat_denom_kernel(
    const int* __restrict__ idx, const float* __restrict__ a_src,
    const float* __restrict__ a_dst, float* __restrict__ denom)
{
    int k = blockIdx.x * 256 + threadIdx.x;
    if (k >= EE) return;
    int s = idx[k];
    int d = idx[EE + k];
    float4 as = *reinterpret_cast<const float4*>(a_src + (size_t)s * 4);
    float4 ad = *reinterpret_cast<const float4*>(a_dst + (size_t)d * 4);
    float e0 = as.x + ad.x; e0 = e0 > 0.f ? e0 : NEG_SLOPE * e0;
    float e1 = as.y + ad.y; e1 = e1 > 0.f ? e1 : NEG_SLOPE * e1;
    float e2 = as.z + ad.z; e2 = e2 > 0.f ? e2 : NEG_SLOPE * e2;
    float e3 = as.w + ad.w; e3 = e3 > 0.f ? e3 : NEG_SLOPE * e3;
    float* db = denom + (size_t)d * 4;
    atomicAdd(db + 0, __expf(e0));
    atomicAdd(db + 1, __expf(e1));
    atomicAdd(db + 2, __expf(e2));
    atomicAdd(db + 3, __expf(e3));
}

__global__ __launch_bounds__(256) void gat_scatter_kernel(
    const int* __restrict__ idx, const float* __restrict__ a_src,
    const float* __restrict__ a_dst, const float* __restrict__ denom,
    const float* __restrict__ xp, float* __restrict__ agg)
{
    int t = blockIdx.x * 256 + threadIdx.x;   // E*32 = 25.6M < 2^31
    int k = t >> 5;
    int c = t & 31;
    if (k >= EE) return;
    int s = idx[k];
    int d = idx[EE + k];
    int h = c >> 3;
    float e = a_src[(size_t)s * 4 + h] + a_dst[(size_t)d * 4 + h];
    e = e > 0.f ? e : NEG_SLOPE * e;
    float alpha = __expf(e) / (denom[(size_t)d * 4 + h] + 1e-16f);
    float4 xv = *reinterpret_cast<const float4*>(xp + (size_t)s * FD + c * 4);
    float* base = agg + (size_t)d * FD + c * 4;
    atomicAdd(base + 0, alpha * xv.x);
    atomicAdd(base + 1, alpha * xv.y);
    atomicAdd(base + 2, alpha * xv.z);
    atomicAdd(base + 3, alpha * xv.w);
}

__global__ __launch_bounds__(256) void gat_elu_kernel(
    const float* __restrict__ agg, float* __restrict__ out)
{
    int i = (blockIdx.x * 256 + threadIdx.x) * 4;
    if (i >= NN * FD) return;
    float4 v = *reinterpret_cast<const float4*>(agg + i);
    float4 r;
    r.x = v.x > 0.f ? v.x : expm1f(v.x);
    r.y = v.y > 0.f ? v.y : expm1f(v.y);
    r.z = v.z > 0.f ? v.z : expm1f(v.z);
    r.w = v.w > 0.f ? v.w : expm1f(v.w);
    *reinterpret_cast<float4*>(out + i) = r;
}

extern "C" void kernel_launch(void* const* d_in, const int* in_sizes, int n_in,
                              void* d_out, int out_size, void* d_ws, size_t ws_size,
                              hipStream_t stream)
{
    const float* x       = (const float*)d_in[0];
    const int*   idx     = (const int*)d_in[1];
    const float* W       = (const float*)d_in[2];
    const float* att_src = (const float*)d_in[3];
    const float* att_dst = (const float*)d_in[4];
    const float* bias    = (const float*)d_in[5];
    const float* skip_W  = (const float*)d_in[6];
    const float* skip_b  = (const float*)d_in[7];
    float*       out     = (float*)d_out;

    float* ws    = (float*)d_ws;
    float* xp    = ws;               // 6,400,000 f32
    float* agg   = ws + 6400000;     // 6,400,000 f32
    float* a_src = ws + 12800000;    //   200,000 f32
    float* a_dst = ws + 13000000;    //   200,000 f32
    float* denom = ws + 13200000;    //   200,000 f32
    // total 53.6 MB

    hipMemsetAsync(denom, 0, (size_t)NN * 4 * sizeof(float), stream);

    gat_gemm_kernel<<<(NN + TN - 1) / TN, 256, 0, stream>>>(
        x, W, skip_W, att_src, att_dst, bias, skip_b, xp, a_src, a_dst, agg);

    gat_denom_kernel<<<(EE + 255) / 256, 256, 0, stream>>>(idx, a_src, a_dst, denom);

    gat_scatter_kernel<<<(EE * 32) / 256, 256, 0, stream>>>(idx, a_src, a_dst, denom, xp, agg);

    gat_elu_kernel<<<(NN * FD / 4) / 256, 256, 0, stream>>>(agg, out);
}

// Round 4
// 390.899 us; speedup vs baseline: 4.3021x; 4.3021x over previous
//
#include <hip/hip_runtime.h>

// GAT residual block: N=50000 nodes, IN=128, H=4 heads, C=32 (H*C=128), E=800000 edges.
// Inputs (all fp32 except edge_index int32): x, edge_index, W, att_src, att_dst, bias, skip_W, skip_b
// Output: float32 [N,128]
//
// Pipeline (no fp32 atomics):
//  K1 gat_gemm:  xp = x@W^T (store), a_src/a_dst logits (store), skip = x@skip_W^T + skip_b + bias
//  K2 hist:      count[d]++ per edge (int atomics)
//  K3 scan:      rowptr = exclusive_scan(count); cursor = copy (single block)
//  K4 fill:      CSR col list: col[atomicAdd(cursor[d])] = src
//  K5 gather:    one wave per dst node: loop CSR edges, acc += exp(e)*xp[src] (regs),
//                denom in same pass; out = elu(skip[d] + acc/denom)
// Segment-max skipped (softmax shift-invariance; |e| <~ 6 -> fp32 exp safe).

#define NN 50000
#define EE 800000
#define FD 128
#define NEG_SLOPE 0.2f

#define TN 16      // nodes per block in GEMM kernel
#define WPAD 132   // padded LDS row stride (floats)

__global__ __launch_bounds__(256) void gat_gemm_kernel(
    const float* __restrict__ x, const float* __restrict__ W,
    const float* __restrict__ skip_W, const float* __restrict__ att_src,
    const float* __restrict__ att_dst, const float* __restrict__ bias,
    const float* __restrict__ skip_b,
    float* __restrict__ xp, float* __restrict__ a_src, float* __restrict__ a_dst,
    float* __restrict__ skip)
{
    __shared__ float xs[TN][FD];     // 8 KB
    __shared__ float Ws[FD][WPAD];   // 66 KB
    const int tid = threadIdx.x;
    const int bn = blockIdx.x * TN;

    for (int i = tid; i < TN * (FD / 4); i += 256) {
        int n = i >> 5;
        int k4 = (i & 31) << 2;
        float4 v = make_float4(0.f, 0.f, 0.f, 0.f);
        int gn = bn + n;
        if (gn < NN) v = *reinterpret_cast<const float4*>(x + (size_t)gn * FD + k4);
        *reinterpret_cast<float4*>(&xs[n][k4]) = v;
    }
    for (int i = tid; i < FD * (FD / 4); i += 256) {
        int j = i >> 5;
        int k4 = (i & 31) << 2;
        *reinterpret_cast<float4*>(&Ws[j][k4]) =
            *reinterpret_cast<const float4*>(W + j * FD + k4);
    }
    __syncthreads();

    const int jg = tid & 31;
    const int ng = tid >> 5;
    const int j0 = jg << 2;
    const int n0 = ng << 1;
    const int h  = jg >> 3;

    float acc[2][4];
    #pragma unroll
    for (int a = 0; a < 2; ++a)
        #pragma unroll
        for (int b = 0; b < 4; ++b) acc[a][b] = 0.f;

    #pragma unroll 4
    for (int k = 0; k < FD; k += 4) {
        float4 xv0 = *reinterpret_cast<const float4*>(&xs[n0][k]);
        float4 xv1 = *reinterpret_cast<const float4*>(&xs[n0 + 1][k]);
        #pragma unroll
        for (int jj = 0; jj < 4; ++jj) {
            float4 wv = *reinterpret_cast<const float4*>(&Ws[j0 + jj][k]);
            acc[0][jj] += xv0.x * wv.x + xv0.y * wv.y + xv0.z * wv.z + xv0.w * wv.w;
            acc[1][jj] += xv1.x * wv.x + xv1.y * wv.y + xv1.z * wv.z + xv1.w * wv.w;
        }
    }

    float4 atts = *reinterpret_cast<const float4*>(att_src + j0);
    float4 attd = *reinterpret_cast<const float4*>(att_dst + j0);
    #pragma unroll
    for (int nn = 0; nn < 2; ++nn) {
        int gn = bn + n0 + nn;
        if (gn < NN)
            *reinterpret_cast<float4*>(xp + (size_t)gn * FD + j0) =
                make_float4(acc[nn][0], acc[nn][1], acc[nn][2], acc[nn][3]);
        float ps = acc[nn][0]*atts.x + acc[nn][1]*atts.y + acc[nn][2]*atts.z + acc[nn][3]*atts.w;
        float pd = acc[nn][0]*attd.x + acc[nn][1]*attd.y + acc[nn][2]*attd.z + acc[nn][3]*attd.w;
        #pragma unroll
        for (int m = 1; m < 8; m <<= 1) {
            ps += __shfl_xor(ps, m, 64);
            pd += __shfl_xor(pd, m, 64);
        }
        if ((jg & 7) == 0 && gn < NN) {
            a_src[gn * 4 + h] = ps;
            a_dst[gn * 4 + h] = pd;
        }
    }

    // phase 2: skip GEMM
    __syncthreads();
    for (int i = tid; i < FD * (FD / 4); i += 256) {
        int j = i >> 5;
        int k4 = (i & 31) << 2;
        *reinterpret_cast<float4*>(&Ws[j][k4]) =
            *reinterpret_cast<const float4*>(skip_W + j * FD + k4);
    }
    __syncthreads();

    float acc2[2][4];
    #pragma unroll
    for (int a = 0; a < 2; ++a)
        #pragma unroll
        for (int b = 0; b < 4; ++b) acc2[a][b] = 0.f;

    #pragma unroll 4
    for (int k = 0; k < FD; k += 4) {
        float4 xv0 = *reinterpret_cast<const float4*>(&xs[n0][k]);
        float4 xv1 = *reinterpret_cast<const float4*>(&xs[n0 + 1][k]);
        #pragma unroll
        for (int jj = 0; jj < 4; ++jj) {
            float4 wv = *reinterpret_cast<const float4*>(&Ws[j0 + jj][k]);
            acc2[0][jj] += xv0.x * wv.x + xv0.y * wv.y + xv0.z * wv.z + xv0.w * wv.w;
            acc2[1][jj] += xv1.x * wv.x + xv1.y * wv.y + xv1.z * wv.z + xv1.w * wv.w;
        }
    }

    float4 sb = *reinterpret_cast<const float4*>(skip_b + j0);
    float4 bb = *reinterpret_cast<const float4*>(bias + j0);
    #pragma unroll
    for (int nn = 0; nn < 2; ++nn) {
        int gn = bn + n0 + nn;
        if (gn < NN)
            *reinterpret_cast<float4*>(skip + (size_t)gn * FD + j0) =
                make_float4(acc2[nn][0] + sb.x + bb.x, acc2[nn][1] + sb.y + bb.y,
                            acc2[nn][2] + sb.z + bb.z, acc2[nn][3] + sb.w + bb.w);
    }
}

__global__ __launch_bounds__(256) void gat_hist_kernel(
    const int* __restrict__ idx, int* __restrict__ count)
{
    int k = blockIdx.x * 256 + threadIdx.x;
    if (k >= EE) return;
    atomicAdd(&count[idx[EE + k]], 1);
}

// single-block hierarchical exclusive scan of count[0..NN) -> rowptr, cursor
__global__ __launch_bounds__(1024) void gat_scan_kernel(
    const int* __restrict__ count, int* __restrict__ rowptr, int* __restrict__ cursor)
{
    __shared__ int wsum[16];
    __shared__ int carry_s;
    const int tid = threadIdx.x;
    const int lane = tid & 63;
    const int wv = tid >> 6;
    if (tid == 0) carry_s = 0;
    __syncthreads();

    for (int base = 0; base < NN; base += 1024) {
        int i = base + tid;
        int v = (i < NN) ? count[i] : 0;
        // wave inclusive scan
        int incl = v;
        #pragma unroll
        for (int off = 1; off < 64; off <<= 1) {
            int t = __shfl_up(incl, off, 64);
            if (lane >= off) incl += t;
        }
        if (lane == 63) wsum[wv] = incl;
        __syncthreads();
        if (wv == 0 && lane < 16) {
            int w = wsum[lane];
            int winc = w;
            #pragma unroll
            for (int off = 1; off < 16; off <<= 1) {
                int t = __shfl_up(winc, off, 64);
                if (lane >= off) winc += t;
            }
            wsum[lane] = winc - w;   // exclusive
        }
        __syncthreads();
        int excl = carry_s + wsum[wv] + incl - v;
        if (i < NN) { rowptr[i] = excl; cursor[i] = excl; }
        __syncthreads();
        if (tid == 1023) carry_s += wsum[15] + incl;   // chunk total
        __syncthreads();
    }
    if (tid == 0) rowptr[NN] = carry_s;
}

__global__ __launch_bounds__(256) void gat_fill_kernel(
    const int* __restrict__ idx, int* __restrict__ cursor, int* __restrict__ col)
{
    int k = blockIdx.x * 256 + threadIdx.x;
    if (k >= EE) return;
    int d = idx[EE + k];
    int pos = atomicAdd(&cursor[d], 1);
    col[pos] = idx[k];
}

// one wave per dst node; lane owns channels (2*lane, 2*lane+1); head = lane>>4
__global__ __launch_bounds__(256) void gat_gather_kernel(
    const int* __restrict__ rowptr, const int* __restrict__ col,
    const float* __restrict__ a_src, const float* __restrict__ a_dst,
    const float* __restrict__ xp, const float* __restrict__ skip,
    float* __restrict__ out)
{
    int wid = (blockIdx.x * 256 + threadIdx.x) >> 6;
    int lane = threadIdx.x & 63;
    if (wid >= NN) return;
    const int d = wid;
    const int h = lane >> 4;
    const float ad = a_dst[(size_t)d * 4 + h];
    const int beg = rowptr[d], end = rowptr[d + 1];

    float accx = 0.f, accy = 0.f, asum = 0.f;
    for (int j = beg; j < end; ++j) {
        int s = col[j];
        float e = a_src[(size_t)s * 4 + h] + ad;
        e = e > 0.f ? e : NEG_SLOPE * e;
        float p = __expf(e);
        asum += p;
        float2 xv = *reinterpret_cast<const float2*>(xp + (size_t)s * FD + lane * 2);
        accx += p * xv.x;
        accy += p * xv.y;
    }
    float inv = 1.f / (asum + 1e-16f);
    float2 sk = *reinterpret_cast<const float2*>(skip + (size_t)d * FD + lane * 2);
    float r0 = sk.x + accx * inv;
    float r1 = sk.y + accy * inv;
    r0 = r0 > 0.f ? r0 : expm1f(r0);
    r1 = r1 > 0.f ? r1 : expm1f(r1);
    float2 r = make_float2(r0, r1);
    *reinterpret_cast<float2*>(out + (size_t)d * FD + lane * 2) = r;
}

extern "C" void kernel_launch(void* const* d_in, const int* in_sizes, int n_in,
                              void* d_out, int out_size, void* d_ws, size_t ws_size,
                              hipStream_t stream)
{
    const float* x       = (const float*)d_in[0];
    const int*   idx     = (const int*)d_in[1];
    const float* W       = (const float*)d_in[2];
    const float* att_src = (const float*)d_in[3];
    const float* att_dst = (const float*)d_in[4];
    const float* bias    = (const float*)d_in[5];
    const float* skip_W  = (const float*)d_in[6];
    const float* skip_b  = (const float*)d_in[7];
    float*       out     = (float*)d_out;

    float* ws    = (float*)d_ws;
    float* xp    = ws;                    // 6,400,000 f32
    float* skip  = ws + 6400000;          // 6,400,000 f32
    float* a_src = ws + 12800000;         //   200,000 f32
    float* a_dst = ws + 13000000;         //   200,000 f32
    int*   count  = (int*)(ws + 13200000);  //  50,000 i32
    int*   rowptr = (int*)(ws + 13252000);  //  50,001 i32
    int*   cursor = (int*)(ws + 13304000);  //  50,000 i32
    int*   col    = (int*)(ws + 13356000);  // 800,000 i32
    // total ~56.6 MB

    hipMemsetAsync(count, 0, (size_t)NN * sizeof(int), stream);

    gat_gemm_kernel<<<(NN + TN - 1) / TN, 256, 0, stream>>>(
        x, W, skip_W, att_src, att_dst, bias, skip_b, xp, a_src, a_dst, skip);

    gat_hist_kernel<<<(EE + 255) / 256, 256, 0, stream>>>(idx, count);
    gat_scan_kernel<<<1, 1024, 0, stream>>>(count, rowptr, cursor);
    gat_fill_kernel<<<(EE + 255) / 256, 256, 0, stream>>>(idx, cursor, col);

    gat_gather_kernel<<<(NN * 64 + 255) / 256, 256, 0, stream>>>(
        rowptr, col, a_src, a_dst, xp, skip, out);
}

// Round 5
// 271.578 us; speedup vs baseline: 6.1922x; 1.4394x over previous
//
#include <hip/hip_runtime.h>

// GAT residual block: N=50000 nodes, IN=128, H=4 heads, C=32 (H*C=128), E=800000 edges.
// Inputs (all fp32 except edge_index int32): x, edge_index, W, att_src, att_dst, bias, skip_W, skip_b
// Output: float32 [N,128]
//
// Pipeline (no fp32 atomics):
//  K1 gat_gemm:  xp = x@W^T, a_src/a_dst logits, skip = x@skip_W^T + skip_b + bias
//                lane jg owns cols j = jg+32*jj (jj == head) -> W row-per-lane, stride-130
//                float2 LDS reads = 2-way bank aliasing (free). Old layout was 16-way conflicted.
//  K2 hist:      count[d]++ (int atomics)
//  K3 blocksum / bscan / scan: parallel 2-level exclusive scan -> rowptr, cursor
//  K4 fill:      col[atomicAdd(cursor[d])] = src
//  K5 gather:    one wave per dst node: acc += exp(e)*xp[src] in regs, denom same pass;
//                out = elu(skip[d] + acc/denom). Unroll-2 for MLP.
// Segment-max skipped (softmax shift-invariance; |e| <~ 6 -> fp32 exp safe).

#define NN 50000
#define EE 800000
#define FD 128
#define NEG_SLOPE 0.2f

#define TN 16      // nodes per block in GEMM kernel (50000 = 3125 * 16, exact)
#define WROW 130   // padded W row stride in floats; float2 reads -> 2-way aliasing (free)
#define SCB 1024   // scan chunk
#define NB_SC ((NN + SCB - 1) / SCB)   // 49

__global__ __launch_bounds__(256) void gat_gemm_kernel(
    const float* __restrict__ x, const float* __restrict__ W,
    const float* __restrict__ skip_W, const float* __restrict__ att_src,
    const float* __restrict__ att_dst, const float* __restrict__ bias,
    const float* __restrict__ skip_b,
    float* __restrict__ xp, float* __restrict__ a_src, float* __restrict__ a_dst,
    float* __restrict__ skip)
{
    __shared__ __align__(16) float xs[TN][FD];    // 8 KB
    __shared__ __align__(16) float Ws[FD][WROW];  // 66.6 KB
    const int tid = threadIdx.x;
    const int bn = blockIdx.x * TN;

    // stage x tile (float4, conflict-free)
    for (int i = tid; i < TN * 32; i += 256) {
        int n = i >> 5;
        int k4 = (i & 31) << 2;
        *reinterpret_cast<float4*>(&xs[n][k4]) =
            *reinterpret_cast<const float4*>(x + (size_t)(bn + n) * FD + k4);
    }
    // stage W: global float4 read, two float2 LDS writes (rows 8B-aligned; full-row span -> no conflict)
    for (int i = tid; i < FD * 32; i += 256) {
        int j = i >> 5;
        int k4 = (i & 31) << 2;
        float4 v = *reinterpret_cast<const float4*>(W + j * FD + k4);
        float2* dst = reinterpret_cast<float2*>(&Ws[j][k4]);
        dst[0] = make_float2(v.x, v.y);
        dst[1] = make_float2(v.z, v.w);
    }
    __syncthreads();

    const int jg = tid & 31;     // channel-within-head lane
    const int ng = tid >> 5;     // node group (8 groups of 2 nodes)
    const int n0 = ng << 1;
    // lane's 4 output columns: j = jg + 32*jj  (jj == head index)

    float atts[4], attd[4];
    #pragma unroll
    for (int jj = 0; jj < 4; ++jj) {
        atts[jj] = att_src[jg + 32 * jj];
        attd[jj] = att_dst[jg + 32 * jj];
    }

    float acc[2][4];
    #pragma unroll
    for (int a = 0; a < 2; ++a)
        #pragma unroll
        for (int b = 0; b < 4; ++b) acc[a][b] = 0.f;

    #pragma unroll 2
    for (int k = 0; k < FD; k += 4) {
        float4 xv0 = *reinterpret_cast<const float4*>(&xs[n0][k]);
        float4 xv1 = *reinterpret_cast<const float4*>(&xs[n0 + 1][k]);
        #pragma unroll
        for (int jj = 0; jj < 4; ++jj) {
            const float* wr = &Ws[jg + 32 * jj][k];
            float2 wa = *reinterpret_cast<const float2*>(wr);
            float2 wb = *reinterpret_cast<const float2*>(wr + 2);
            acc[0][jj] += xv0.x * wa.x + xv0.y * wa.y + xv0.z * wb.x + xv0.w * wb.y;
            acc[1][jj] += xv1.x * wa.x + xv1.y * wa.y + xv1.z * wb.x + xv1.w * wb.y;
        }
    }

    #pragma unroll
    for (int nn = 0; nn < 2; ++nn) {
        int gn = bn + n0 + nn;
        #pragma unroll
        for (int jj = 0; jj < 4; ++jj)
            xp[(size_t)gn * FD + jg + 32 * jj] = acc[nn][jj];
        float p0 = acc[nn][0] * atts[0], p1 = acc[nn][1] * atts[1];
        float p2 = acc[nn][2] * atts[2], p3 = acc[nn][3] * atts[3];
        float q0 = acc[nn][0] * attd[0], q1 = acc[nn][1] * attd[1];
        float q2 = acc[nn][2] * attd[2], q3 = acc[nn][3] * attd[3];
        #pragma unroll
        for (int m = 1; m < 32; m <<= 1) {
            p0 += __shfl_xor(p0, m, 32); p1 += __shfl_xor(p1, m, 32);
            p2 += __shfl_xor(p2, m, 32); p3 += __shfl_xor(p3, m, 32);
            q0 += __shfl_xor(q0, m, 32); q1 += __shfl_xor(q1, m, 32);
            q2 += __shfl_xor(q2, m, 32); q3 += __shfl_xor(q3, m, 32);
        }
        if (jg == 0) {
            *reinterpret_cast<float4*>(a_src + (size_t)gn * 4) = make_float4(p0, p1, p2, p3);
            *reinterpret_cast<float4*>(a_dst + (size_t)gn * 4) = make_float4(q0, q1, q2, q3);
        }
    }

    // phase 2: skip GEMM (restage Ws with skip_W)
    __syncthreads();
    for (int i = tid; i < FD * 32; i += 256) {
        int j = i >> 5;
        int k4 = (i & 31) << 2;
        float4 v = *reinterpret_cast<const float4*>(skip_W + j * FD + k4);
        float2* dst = reinterpret_cast<float2*>(&Ws[j][k4]);
        dst[0] = make_float2(v.x, v.y);
        dst[1] = make_float2(v.z, v.w);
    }
    __syncthreads();

    float sb[4];
    #pragma unroll
    for (int jj = 0; jj < 4; ++jj)
        sb[jj] = skip_b[jg + 32 * jj] + bias[jg + 32 * jj];

    float acc2[2][4];
    #pragma unroll
    for (int a = 0; a < 2; ++a)
        #pragma unroll
        for (int b = 0; b < 4; ++b) acc2[a][b] = 0.f;

    #pragma unroll 2
    for (int k = 0; k < FD; k += 4) {
        float4 xv0 = *reinterpret_cast<const float4*>(&xs[n0][k]);
        float4 xv1 = *reinterpret_cast<const float4*>(&xs[n0 + 1][k]);
        #pragma unroll
        for (int jj = 0; jj < 4; ++jj) {
            const float* wr = &Ws[jg + 32 * jj][k];
            float2 wa = *reinterpret_cast<const float2*>(wr);
            float2 wb = *reinterpret_cast<const float2*>(wr + 2);
            acc2[0][jj] += xv0.x * wa.x + xv0.y * wa.y + xv0.z * wb.x + xv0.w * wb.y;
            acc2[1][jj] += xv1.x * wa.x + xv1.y * wa.y + xv1.z * wb.x + xv1.w * wb.y;
        }
    }

    #pragma unroll
    for (int nn = 0; nn < 2; ++nn) {
        int gn = bn + n0 + nn;
        #pragma unroll
        for (int jj = 0; jj < 4; ++jj)
            skip[(size_t)gn * FD + jg + 32 * jj] = acc2[nn][jj] + sb[jj];
    }
}

__global__ __launch_bounds__(256) void gat_hist_kernel(
    const int* __restrict__ idx, int* __restrict__ count)
{
    int k = blockIdx.x * 256 + threadIdx.x;
    if (k >= EE) return;
    atomicAdd(&count[idx[EE + k]], 1);
}

__global__ __launch_bounds__(1024) void gat_blocksum_kernel(
    const int* __restrict__ count, int* __restrict__ bsum)
{
    __shared__ int ws[16];
    int tid = threadIdx.x, lane = tid & 63, wv = tid >> 6;
    int i = blockIdx.x * SCB + tid;
    int v = (i < NN) ? count[i] : 0;
    #pragma unroll
    for (int off = 32; off; off >>= 1) v += __shfl_down(v, off, 64);
    if (lane == 0) ws[wv] = v;
    __syncthreads();
    if (wv == 0) {
        int t = (lane < 16) ? ws[lane] : 0;
        #pragma unroll
        for (int off = 8; off; off >>= 1) t += __shfl_down(t, off, 64);
        if (lane == 0) bsum[blockIdx.x] = t;
    }
}

__global__ void gat_bscan_kernel(const int* __restrict__ bsum, int* __restrict__ boff)
{
    int lane = threadIdx.x;  // 64 threads, NB_SC=49 <= 64
    int v = (lane < NB_SC) ? bsum[lane] : 0;
    int incl = v;
    #pragma unroll
    for (int off = 1; off < 64; off <<= 1) {
        int t = __shfl_up(incl, off, 64);
        if (lane >= off) incl += t;
    }
    if (lane < NB_SC) boff[lane] = incl - v;
}

__global__ __launch_bounds__(1024) void gat_scan_kernel(
    const int* __restrict__ count, const int* __restrict__ boff,
    int* __restrict__ rowptr, int* __restrict__ cursor)
{
    __shared__ int ws[16];
    int tid = threadIdx.x, lane = tid & 63, wv = tid >> 6;
    int i = blockIdx.x * SCB + tid;
    int v = (i < NN) ? count[i] : 0;
    int incl = v;
    #pragma unroll
    for (int off = 1; off < 64; off <<= 1) {
        int t = __shfl_up(incl, off, 64);
        if (lane >= off) incl += t;
    }
    if (lane == 63) ws[wv] = incl;
    __syncthreads();
    if (wv == 0) {
        int t = (lane < 16) ? ws[lane] : 0;
        int winc = t;
        #pragma unroll
        for (int off = 1; off < 16; off <<= 1) {
            int u = __shfl_up(winc, off, 64);
            if (lane >= off) winc += u;
        }
        if (lane < 16) ws[lane] = winc - t;
    }
    __syncthreads();
    int excl = boff[blockIdx.x] + ws[wv] + incl - v;
    if (i < NN) { rowptr[i] = excl; cursor[i] = excl; }
    if (blockIdx.x == 0 && tid == 0) rowptr[NN] = EE;
}

__global__ __launch_bounds__(256) void gat_fill_kernel(
    const int* __restrict__ idx, int* __restrict__ cursor, int* __restrict__ col)
{
    int k = blockIdx.x * 256 + threadIdx.x;
    if (k >= EE) return;
    int d = idx[EE + k];
    int pos = atomicAdd(&cursor[d], 1);
    col[pos] = idx[k];
}

// one wave per dst node; lane owns channels (2*lane, 2*lane+1); head = lane>>4
__global__ __launch_bounds__(256) void gat_gather_kernel(
    const int* __restrict__ rowptr, const int* __restrict__ col,
    const float* __restrict__ a_src, const float* __restrict__ a_dst,
    const float* __restrict__ xp, const float* __restrict__ skip,
    float* __restrict__ out)
{
    int wid = (blockIdx.x * 256 + threadIdx.x) >> 6;
    int lane = threadIdx.x & 63;
    if (wid >= NN) return;
    const int d = wid;
    const int h = lane >> 4;
    const float ad = a_dst[(size_t)d * 4 + h];
    const int beg = rowptr[d], end = rowptr[d + 1];

    float accx = 0.f, accy = 0.f, asum = 0.f;
    int j = beg;
    for (; j + 2 <= end; j += 2) {
        int s0 = col[j], s1 = col[j + 1];
        float e0 = a_src[(size_t)s0 * 4 + h] + ad;
        float e1 = a_src[(size_t)s1 * 4 + h] + ad;
        float2 x0 = *reinterpret_cast<const float2*>(xp + (size_t)s0 * FD + lane * 2);
        float2 x1 = *reinterpret_cast<const float2*>(xp + (size_t)s1 * FD + lane * 2);
        e0 = e0 > 0.f ? e0 : NEG_SLOPE * e0;
        e1 = e1 > 0.f ? e1 : NEG_SLOPE * e1;
        float p0 = __expf(e0), p1 = __expf(e1);
        asum += p0 + p1;
        accx += p0 * x0.x + p1 * x1.x;
        accy += p0 * x0.y + p1 * x1.y;
    }
    if (j < end) {
        int s = col[j];
        float e = a_src[(size_t)s * 4 + h] + ad;
        float2 xv = *reinterpret_cast<const float2*>(xp + (size_t)s * FD + lane * 2);
        e = e > 0.f ? e : NEG_SLOPE * e;
        float p = __expf(e);
        asum += p;
        accx += p * xv.x;
        accy += p * xv.y;
    }
    float inv = 1.f / (asum + 1e-16f);
    float2 sk = *reinterpret_cast<const float2*>(skip + (size_t)d * FD + lane * 2);
    float r0 = sk.x + accx * inv;
    float r1 = sk.y + accy * inv;
    r0 = r0 > 0.f ? r0 : expm1f(r0);
    r1 = r1 > 0.f ? r1 : expm1f(r1);
    *reinterpret_cast<float2*>(out + (size_t)d * FD + lane * 2) = make_float2(r0, r1);
}

extern "C" void kernel_launch(void* const* d_in, const int* in_sizes, int n_in,
                              void* d_out, int out_size, void* d_ws, size_t ws_size,
                              hipStream_t stream)
{
    const float* x       = (const float*)d_in[0];
    const int*   idx     = (const int*)d_in[1];
    const float* W       = (const float*)d_in[2];
    const float* att_src = (const float*)d_in[3];
    const float* att_dst = (const float*)d_in[4];
    const float* bias    = (const float*)d_in[5];
    const float* skip_W  = (const float*)d_in[6];
    const float* skip_b  = (const float*)d_in[7];
    float*       out     = (float*)d_out;

    float* ws    = (float*)d_ws;
    float* xp    = ws;                      // 6,400,000 f32
    float* skip  = ws + 6400000;            // 6,400,000 f32
    float* a_src = ws + 12800000;           //   200,000 f32
    float* a_dst = ws + 13000000;           //   200,000 f32
    int*   count  = (int*)(ws + 13200000);  //    50,000 i32
    int*   rowptr = (int*)(ws + 13252000);  //    50,001 i32
    int*   cursor = (int*)(ws + 13304000);  //    50,000 i32
    int*   col    = (int*)(ws + 13356000);  //   800,000 i32
    int*   bsum   = (int*)(ws + 14200000);  //        49 i32
    int*   boff   = (int*)(ws + 14200064);  //        49 i32
    // total ~56.8 MB

    hipMemsetAsync(count, 0, (size_t)NN * sizeof(int), stream);

    gat_gemm_kernel<<<NN / TN, 256, 0, stream>>>(
        x, W, skip_W, att_src, att_dst, bias, skip_b, xp, a_src, a_dst, skip);

    gat_hist_kernel<<<(EE + 255) / 256, 256, 0, stream>>>(idx, count);
    gat_blocksum_kernel<<<NB_SC, SCB, 0, stream>>>(count, bsum);
    gat_bscan_kernel<<<1, 64, 0, stream>>>(bsum, boff);
    gat_scan_kernel<<<NB_SC, SCB, 0, stream>>>(count, boff, rowptr, cursor);
    gat_fill_kernel<<<(EE + 255) / 256, 256, 0, stream>>>(idx, cursor, col);

    gat_gather_kernel<<<(NN * 64) / 256, 256, 0, stream>>>(
        rowptr, col, a_src, a_dst, xp, skip, out);
}

// Round 6
// 200.957 us; speedup vs baseline: 8.3683x; 1.3514x over previous
//
#include <hip/hip_runtime.h>
#include <hip/hip_bf16.h>

// GAT residual block: N=50000, IN=128, H=4, C=32 (H*C=128), E=800000.
// Inputs fp32 (edge_index int32): x, edge_index, W, att_src, att_dst, bias, skip_W, skip_b
// Output: float32 [N,128]
//
// Pipeline:
//  conv_x: xb = bf16(x)            conv_w: wb = bf16([W; skip_W])  (256x128)
//  mfma:   per 16-row strip, 4 waves x 64 cols, mfma_f32_16x16x32_bf16, K=128.
//          Waves 0,1 -> xpb (bf16 store) + a_src/a_dst logits (fp32 epilogue reduce).
//          Waves 2,3 -> skip = x@skip_W^T + skip_b + bias (fp32 store).
//          A/B frags read 16B contiguous-k direct from global (no LDS, no conflicts).
//  hist/blocksum/bscan/scan/fill: CSR build (int atomics + 2-level scan)
//  gather: one wave per dst: acc += exp(e)*xpb[src] (bf16 row = 256B/edge), denom same
//          pass; out = elu(skip + acc/denom).
// Segment-max skipped (softmax shift invariance, |e| <~ 6).

#define NN 50000
#define EE 800000
#define FD 128
#define NEG_SLOPE 0.2f

#define SCB 1024
#define NB_SC ((NN + SCB - 1) / SCB)   // 49

typedef __attribute__((ext_vector_type(8))) short short8;   // 8 bf16 = 4 VGPR
typedef __attribute__((ext_vector_type(4))) float f32x4;

__device__ inline ushort f2b(float f) {
    __hip_bfloat16 h = __float2bfloat16(f);
    return *reinterpret_cast<ushort*>(&h);
}
__device__ inline float b2f(ushort u) {
    union { float f; unsigned int i; } c;
    c.i = ((unsigned int)u) << 16;
    return c.f;
}

__global__ __launch_bounds__(256) void conv_x_kernel(
    const float* __restrict__ x, ushort* __restrict__ xb)
{
    int i = (blockIdx.x * 256 + threadIdx.x) * 4;   // exact: 6.4M/4/256 = 6250 blocks
    float4 v = *reinterpret_cast<const float4*>(x + i);
    ushort4 o;
    o.x = f2b(v.x); o.y = f2b(v.y); o.z = f2b(v.z); o.w = f2b(v.w);
    *reinterpret_cast<ushort4*>(xb + i) = o;
}

__global__ __launch_bounds__(256) void conv_w_kernel(
    const float* __restrict__ W, const float* __restrict__ skip_W,
    ushort* __restrict__ wb)
{
    int i = (blockIdx.x * 256 + threadIdx.x) * 4;   // 32768/4/256 = 32 blocks
    int row = i >> 7;
    int colb = i & 127;
    const float* src = (row < 128) ? (W + row * FD + colb) : (skip_W + (row - 128) * FD + colb);
    float4 v = *reinterpret_cast<const float4*>(src);
    ushort4 o;
    o.x = f2b(v.x); o.y = f2b(v.y); o.z = f2b(v.z); o.w = f2b(v.w);
    *reinterpret_cast<ushort4*>(wb + i) = o;
}

// grid = 3125 (one 16-row strip per block), 4 waves.
// wave w: is_skip = w>>1, ncb = (w&1)*64. Covers cols [base+ncb, base+ncb+64).
__global__ __launch_bounds__(256) void gat_mfma_kernel(
    const ushort* __restrict__ xb, const ushort* __restrict__ wb,
    const float* __restrict__ att_src, const float* __restrict__ att_dst,
    const float* __restrict__ bias, const float* __restrict__ skip_b,
    ushort* __restrict__ xpb, float* __restrict__ a_src, float* __restrict__ a_dst,
    float* __restrict__ skip)
{
    const int tid = threadIdx.x;
    const int w = tid >> 6;
    const int l = tid & 63;
    const int lrow = l & 15;
    const int lgrp = l >> 4;
    const int m0 = blockIdx.x * 16;
    const int is_skip = w >> 1;
    const int ncb = (w & 1) * 64;

    // B frags: wb row j = is_skip*128 + ncb + t*16 + lrow; k = kk*32 + lgrp*8 .. +8
    short8 bfrag[4][4];
    const ushort* wbase = wb + (size_t)(is_skip * 128 + ncb) * FD;
    #pragma unroll
    for (int t = 0; t < 4; ++t)
        #pragma unroll
        for (int kk = 0; kk < 4; ++kk)
            bfrag[t][kk] = *reinterpret_cast<const short8*>(
                wbase + (size_t)(t * 16 + lrow) * FD + kk * 32 + lgrp * 8);

    // A frags: xb row m0+lrow, same k slicing
    short8 afrag[4];
    #pragma unroll
    for (int kk = 0; kk < 4; ++kk)
        afrag[kk] = *reinterpret_cast<const short8*>(
            xb + (size_t)(m0 + lrow) * FD + kk * 32 + lgrp * 8);

    f32x4 acc[4];
    #pragma unroll
    for (int t = 0; t < 4; ++t) acc[t] = (f32x4){0.f, 0.f, 0.f, 0.f};

    #pragma unroll
    for (int kk = 0; kk < 4; ++kk)
        #pragma unroll
        for (int t = 0; t < 4; ++t)
            acc[t] = __builtin_amdgcn_mfma_f32_16x16x32_bf16(
                afrag[kk], bfrag[t][kk], acc[t], 0, 0, 0);

    // C/D layout: element (row = 4*lgrp + r, col = lrow) in tile t; col_t = ncb + t*16 + lrow
    if (is_skip) {
        #pragma unroll
        for (int t = 0; t < 4; ++t) {
            int colt = ncb + t * 16 + lrow;
            float add = skip_b[colt] + bias[colt];
            #pragma unroll
            for (int r = 0; r < 4; ++r) {
                int row = m0 + lgrp * 4 + r;
                skip[(size_t)row * FD + colt] = acc[t][r] + add;
            }
        }
    } else {
        float as[4], ad[4];
        #pragma unroll
        for (int t = 0; t < 4; ++t) {
            int colt = ncb + t * 16 + lrow;
            as[t] = att_src[colt];
            ad[t] = att_dst[colt];
            #pragma unroll
            for (int r = 0; r < 4; ++r) {
                int row = m0 + lgrp * 4 + r;
                xpb[(size_t)row * FD + colt] = f2b(acc[t][r]);
            }
        }
        // logits: head h0 = ncb>>5 (tiles 0,1), h0+1 (tiles 2,3); reduce over 16 lanes
        const int h0 = ncb >> 5;
        #pragma unroll
        for (int r = 0; r < 4; ++r) {
            float p0 = acc[0][r] * as[0] + acc[1][r] * as[1];
            float p1 = acc[2][r] * as[2] + acc[3][r] * as[3];
            float q0 = acc[0][r] * ad[0] + acc[1][r] * ad[1];
            float q1 = acc[2][r] * ad[2] + acc[3][r] * ad[3];
            #pragma unroll
            for (int m = 1; m < 16; m <<= 1) {
                p0 += __shfl_xor(p0, m, 64);
                p1 += __shfl_xor(p1, m, 64);
                q0 += __shfl_xor(q0, m, 64);
                q1 += __shfl_xor(q1, m, 64);
            }
            if (lrow == 0) {
                int row = m0 + lgrp * 4 + r;
                a_src[(size_t)row * 4 + h0]     = p0;
                a_src[(size_t)row * 4 + h0 + 1] = p1;
                a_dst[(size_t)row * 4 + h0]     = q0;
                a_dst[(size_t)row * 4 + h0 + 1] = q1;
            }
        }
    }
}

__global__ __launch_bounds__(256) void gat_hist_kernel(
    const int* __restrict__ idx, int* __restrict__ count)
{
    int k = blockIdx.x * 256 + threadIdx.x;
    if (k >= EE) return;
    atomicAdd(&count[idx[EE + k]], 1);
}

__global__ __launch_bounds__(1024) void gat_blocksum_kernel(
    const int* __restrict__ count, int* __restrict__ bsum)
{
    __shared__ int ws[16];
    int tid = threadIdx.x, lane = tid & 63, wv = tid >> 6;
    int i = blockIdx.x * SCB + tid;
    int v = (i < NN) ? count[i] : 0;
    #pragma unroll
    for (int off = 32; off; off >>= 1) v += __shfl_down(v, off, 64);
    if (lane == 0) ws[wv] = v;
    __syncthreads();
    if (wv == 0) {
        int t = (lane < 16) ? ws[lane] : 0;
        #pragma unroll
        for (int off = 8; off; off >>= 1) t += __shfl_down(t, off, 64);
        if (lane == 0) bsum[blockIdx.x] = t;
    }
}

__global__ void gat_bscan_kernel(const int* __restrict__ bsum, int* __restrict__ boff)
{
    int lane = threadIdx.x;
    int v = (lane < NB_SC) ? bsum[lane] : 0;
    int incl = v;
    #pragma unroll
    for (int off = 1; off < 64; off <<= 1) {
        int t = __shfl_up(incl, off, 64);
        if (lane >= off) incl += t;
    }
    if (lane < NB_SC) boff[lane] = incl - v;
}

__global__ __launch_bounds__(1024) void gat_scan_kernel(
    const int* __restrict__ count, const int* __restrict__ boff,
    int* __restrict__ rowptr, int* __restrict__ cursor)
{
    __shared__ int ws[16];
    int tid = threadIdx.x, lane = tid & 63, wv = tid >> 6;
    int i = blockIdx.x * SCB + tid;
    int v = (i < NN) ? count[i] : 0;
    int incl = v;
    #pragma unroll
    for (int off = 1; off < 64; off <<= 1) {
        int t = __shfl_up(incl, off, 64);
        if (lane >= off) incl += t;
    }
    if (lane == 63) ws[wv] = incl;
    __syncthreads();
    if (wv == 0) {
        int t = (lane < 16) ? ws[lane] : 0;
        int winc = t;
        #pragma unroll
        for (int off = 1; off < 16; off <<= 1) {
            int u = __shfl_up(winc, off, 64);
            if (lane >= off) winc += u;
        }
        if (lane < 16) ws[lane] = winc - t;
    }
    __syncthreads();
    int excl = boff[blockIdx.x] + ws[wv] + incl - v;
    if (i < NN) { rowptr[i] = excl; cursor[i] = excl; }
    if (blockIdx.x == 0 && tid == 0) rowptr[NN] = EE;
}

__global__ __launch_bounds__(256) void gat_fill_kernel(
    const int* __restrict__ idx, int* __restrict__ cursor, int* __restrict__ col)
{
    int k = blockIdx.x * 256 + threadIdx.x;
    if (k >= EE) return;
    int d = idx[EE + k];
    int pos = atomicAdd(&cursor[d], 1);
    col[pos] = idx[k];
}

// one wave per dst node; lane owns channels (2*lane, 2*lane+1); head = lane>>4
__global__ __launch_bounds__(256) void gat_gather_kernel(
    const int* __restrict__ rowptr, const int* __restrict__ col,
    const float* __restrict__ a_src, const float* __restrict__ a_dst,
    const ushort* __restrict__ xpb, const float* __restrict__ skip,
    float* __restrict__ out)
{
    int wid = (blockIdx.x * 256 + threadIdx.x) >> 6;
    int lane = threadIdx.x & 63;
    if (wid >= NN) return;
    const int d = wid;
    const int h = lane >> 4;
    const float ad = a_dst[(size_t)d * 4 + h];
    const int beg = rowptr[d], end = rowptr[d + 1];

    float accx = 0.f, accy = 0.f, asum = 0.f;
    int j = beg;
    for (; j + 2 <= end; j += 2) {
        int s0 = col[j], s1 = col[j + 1];
        float e0 = a_src[(size_t)s0 * 4 + h] + ad;
        float e1 = a_src[(size_t)s1 * 4 + h] + ad;
        ushort2 x0 = *reinterpret_cast<const ushort2*>(xpb + (size_t)s0 * FD + lane * 2);
        ushort2 x1 = *reinterpret_cast<const ushort2*>(xpb + (size_t)s1 * FD + lane * 2);
        e0 = e0 > 0.f ? e0 : NEG_SLOPE * e0;
        e1 = e1 > 0.f ? e1 : NEG_SLOPE * e1;
        float p0 = __expf(e0), p1 = __expf(e1);
        asum += p0 + p1;
        accx += p0 * b2f(x0.x) + p1 * b2f(x1.x);
        accy += p0 * b2f(x0.y) + p1 * b2f(x1.y);
    }
    if (j < end) {
        int s = col[j];
        float e = a_src[(size_t)s * 4 + h] + ad;
        ushort2 xv = *reinterpret_cast<const ushort2*>(xpb + (size_t)s * FD + lane * 2);
        e = e > 0.f ? e : NEG_SLOPE * e;
        float p = __expf(e);
        asum += p;
        accx += p * b2f(xv.x);
        accy += p * b2f(xv.y);
    }
    float inv = 1.f / (asum + 1e-16f);
    float2 sk = *reinterpret_cast<const float2*>(skip + (size_t)d * FD + lane * 2);
    float r0 = sk.x + accx * inv;
    float r1 = sk.y + accy * inv;
    r0 = r0 > 0.f ? r0 : expm1f(r0);
    r1 = r1 > 0.f ? r1 : expm1f(r1);
    *reinterpret_cast<float2*>(out + (size_t)d * FD + lane * 2) = make_float2(r0, r1);
}

extern "C" void kernel_launch(void* const* d_in, const int* in_sizes, int n_in,
                              void* d_out, int out_size, void* d_ws, size_t ws_size,
                              hipStream_t stream)
{
    const float* x       = (const float*)d_in[0];
    const int*   idx     = (const int*)d_in[1];
    const float* W       = (const float*)d_in[2];
    const float* att_src = (const float*)d_in[3];
    const float* att_dst = (const float*)d_in[4];
    const float* bias    = (const float*)d_in[5];
    const float* skip_W  = (const float*)d_in[6];
    const float* skip_b  = (const float*)d_in[7];
    float*       out     = (float*)d_out;

    float*  ws     = (float*)d_ws;
    float*  skip   = ws;                         // 6,400,000 f32
    float*  a_src  = ws + 6400000;               //   200,000 f32
    float*  a_dst  = ws + 6600000;               //   200,000 f32
    int*    count  = (int*)(ws + 6800000);       //    50,000 i32
    int*    rowptr = (int*)(ws + 6852000);       //    50,001 i32
    int*    cursor = (int*)(ws + 6904000);       //    50,000 i32
    int*    col    = (int*)(ws + 6956000);       //   800,000 i32
    int*    bsum   = (int*)(ws + 7800000);       //        49 i32
    int*    boff   = (int*)(ws + 7800064);       //        49 i32
    ushort* xb     = (ushort*)(ws + 7900000);    // 6,400,000 u16 (3.2M f32 slots)
    ushort* xpb    = (ushort*)(ws + 11100000);   // 6,400,000 u16
    ushort* wb     = (ushort*)(ws + 14300000);   //    32,768 u16
    // total ~57.3 MB (<= previous rounds' footprint)

    hipMemsetAsync(count, 0, (size_t)NN * sizeof(int), stream);

    conv_x_kernel<<<NN * FD / 4 / 256, 256, 0, stream>>>(x, xb);
    conv_w_kernel<<<256 * FD / 4 / 256, 256, 0, stream>>>(W, skip_W, wb);

    gat_mfma_kernel<<<NN / 16, 256, 0, stream>>>(
        xb, wb, att_src, att_dst, bias, skip_b, xpb, a_src, a_dst, skip);

    gat_hist_kernel<<<(EE + 255) / 256, 256, 0, stream>>>(idx, count);
    gat_blocksum_kernel<<<NB_SC, SCB, 0, stream>>>(count, bsum);
    gat_bscan_kernel<<<1, 64, 0, stream>>>(bsum, boff);
    gat_scan_kernel<<<NB_SC, SCB, 0, stream>>>(count, boff, rowptr, cursor);
    gat_fill_kernel<<<(EE + 255) / 256, 256, 0, stream>>>(idx, cursor, col);

    gat_gather_kernel<<<(NN * 64) / 256, 256, 0, stream>>>(
        rowptr, col, a_src, a_dst, xpb, skip, out);
}

// Round 7
// 179.616 us; speedup vs baseline: 9.3626x; 1.1188x over previous
//
#include <hip/hip_runtime.h>
#include <hip/hip_bf16.h>

// GAT residual block: N=50000, IN=128, H=4, C=32 (H*C=128), E=800000.
// Inputs fp32 (edge_index int32): x, edge_index, W, att_src, att_dst, bias, skip_W, skip_b
// Output: float32 [N,128]
//
// 7 dispatches:
//  memset(count)
//  K1 pre:    blocks 0..3124: hist count[d]++ ; blocks 3125..3156: wb = bf16([W; skip_W])
//  K2 mfma:   per 16-row strip, 4 waves x 64 cols, mfma_f32_16x16x32_bf16, K=128.
//             A-frags: read fp32 x directly, convert to bf16 in-register (conv_x fused).
//             Waves 0,1 -> xpb (bf16) + a_src/a_dst logits; waves 2,3 -> skip + skip_b + bias.
//  K3 blocksum: per-1024-chunk sums of count
//  K4 scan:   2-level exclusive scan (block prefix of bsum computed inline by wave 1)
//  K5 fill:   col[atomicAdd(cursor[d])] = src
//  K6 gather: one wave per dst, unroll-4 edge loop: acc += exp(e)*xpb[src], denom same
//             pass; out = elu(skip + acc/denom).
// Segment-max skipped (softmax shift invariance, |e| <~ 6).

#define NN 50000
#define EE 800000
#define FD 128
#define NEG_SLOPE 0.2f

#define SCB 1024
#define NB_SC ((NN + SCB - 1) / SCB)   // 49
#define NB_HIST (EE / 256)             // 3125
#define NB_CONVW 32                    // 32768 elems / 4 / 256

typedef __attribute__((ext_vector_type(8))) short short8;   // 8 bf16 = 4 VGPR
typedef __attribute__((ext_vector_type(4))) float f32x4;

__device__ inline ushort f2b(float f) {
    __hip_bfloat16 h = __float2bfloat16(f);
    return *reinterpret_cast<ushort*>(&h);
}
__device__ inline float b2f(ushort u) {
    union { float f; unsigned int i; } c;
    c.i = ((unsigned int)u) << 16;
    return c.f;
}

// blocks [0, NB_HIST): histogram; blocks [NB_HIST, NB_HIST+NB_CONVW): W conversion
__global__ __launch_bounds__(256) void gat_pre_kernel(
    const int* __restrict__ idx, int* __restrict__ count,
    const float* __restrict__ W, const float* __restrict__ skip_W,
    ushort* __restrict__ wb)
{
    int b = blockIdx.x;
    if (b < NB_HIST) {
        int k = b * 256 + threadIdx.x;          // exact: 3125*256 = 800000
        atomicAdd(&count[idx[EE + k]], 1);
    } else {
        int i = ((b - NB_HIST) * 256 + threadIdx.x) * 4;   // < 32768
        int row = i >> 7;
        int colb = i & 127;
        const float* src = (row < 128) ? (W + row * FD + colb)
                                       : (skip_W + (row - 128) * FD + colb);
        float4 v = *reinterpret_cast<const float4*>(src);
        ushort4 o;
        o.x = f2b(v.x); o.y = f2b(v.y); o.z = f2b(v.z); o.w = f2b(v.w);
        *reinterpret_cast<ushort4*>(wb + i) = o;
    }
}

// grid = 3125 (one 16-row strip per block), 4 waves.
// wave w: is_skip = w>>1, ncb = (w&1)*64.
__global__ __launch_bounds__(256) void gat_mfma_kernel(
    const float* __restrict__ x, const ushort* __restrict__ wb,
    const float* __restrict__ att_src, const float* __restrict__ att_dst,
    const float* __restrict__ bias, const float* __restrict__ skip_b,
    ushort* __restrict__ xpb, float* __restrict__ a_src, float* __restrict__ a_dst,
    float* __restrict__ skip)
{
    const int tid = threadIdx.x;
    const int w = tid >> 6;
    const int l = tid & 63;
    const int lrow = l & 15;
    const int lgrp = l >> 4;
    const int m0 = blockIdx.x * 16;
    const int is_skip = w >> 1;
    const int ncb = (w & 1) * 64;

    // B frags: wb row j = is_skip*128 + ncb + t*16 + lrow; k = kk*32 + lgrp*8 .. +8
    short8 bfrag[4][4];
    const ushort* wbase = wb + (size_t)(is_skip * 128 + ncb) * FD;
    #pragma unroll
    for (int t = 0; t < 4; ++t)
        #pragma unroll
        for (int kk = 0; kk < 4; ++kk)
            bfrag[t][kk] = *reinterpret_cast<const short8*>(
                wbase + (size_t)(t * 16 + lrow) * FD + kk * 32 + lgrp * 8);

    // A frags: fp32 x row m0+lrow, k = kk*32 + lgrp*8 .. +8, converted in-register
    short8 afrag[4];
    const float* xrow = x + (size_t)(m0 + lrow) * FD + lgrp * 8;
    #pragma unroll
    for (int kk = 0; kk < 4; ++kk) {
        float4 a0 = *reinterpret_cast<const float4*>(xrow + kk * 32);
        float4 a1 = *reinterpret_cast<const float4*>(xrow + kk * 32 + 4);
        short8 af;
        af[0] = f2b(a0.x); af[1] = f2b(a0.y); af[2] = f2b(a0.z); af[3] = f2b(a0.w);
        af[4] = f2b(a1.x); af[5] = f2b(a1.y); af[6] = f2b(a1.z); af[7] = f2b(a1.w);
        afrag[kk] = af;
    }

    f32x4 acc[4];
    #pragma unroll
    for (int t = 0; t < 4; ++t) acc[t] = (f32x4){0.f, 0.f, 0.f, 0.f};

    #pragma unroll
    for (int kk = 0; kk < 4; ++kk)
        #pragma unroll
        for (int t = 0; t < 4; ++t)
            acc[t] = __builtin_amdgcn_mfma_f32_16x16x32_bf16(
                afrag[kk], bfrag[t][kk], acc[t], 0, 0, 0);

    // C/D: element (row = 4*lgrp + r, col = lrow) of tile t; col_t = ncb + t*16 + lrow
    if (is_skip) {
        #pragma unroll
        for (int t = 0; t < 4; ++t) {
            int colt = ncb + t * 16 + lrow;
            float add = skip_b[colt] + bias[colt];
            #pragma unroll
            for (int r = 0; r < 4; ++r) {
                int row = m0 + lgrp * 4 + r;
                skip[(size_t)row * FD + colt] = acc[t][r] + add;
            }
        }
    } else {
        float as[4], ad[4];
        #pragma unroll
        for (int t = 0; t < 4; ++t) {
            int colt = ncb + t * 16 + lrow;
            as[t] = att_src[colt];
            ad[t] = att_dst[colt];
            #pragma unroll
            for (int r = 0; r < 4; ++r) {
                int row = m0 + lgrp * 4 + r;
                xpb[(size_t)row * FD + colt] = f2b(acc[t][r]);
            }
        }
        const int h0 = ncb >> 5;   // tiles 0,1 -> head h0; tiles 2,3 -> head h0+1
        #pragma unroll
        for (int r = 0; r < 4; ++r) {
            float p0 = acc[0][r] * as[0] + acc[1][r] * as[1];
            float p1 = acc[2][r] * as[2] + acc[3][r] * as[3];
            float q0 = acc[0][r] * ad[0] + acc[1][r] * ad[1];
            float q1 = acc[2][r] * ad[2] + acc[3][r] * ad[3];
            #pragma unroll
            for (int m = 1; m < 16; m <<= 1) {
                p0 += __shfl_xor(p0, m, 64);
                p1 += __shfl_xor(p1, m, 64);
                q0 += __shfl_xor(q0, m, 64);
                q1 += __shfl_xor(q1, m, 64);
            }
            if (lrow == 0) {
                int row = m0 + lgrp * 4 + r;
                a_src[(size_t)row * 4 + h0]     = p0;
                a_src[(size_t)row * 4 + h0 + 1] = p1;
                a_dst[(size_t)row * 4 + h0]     = q0;
                a_dst[(size_t)row * 4 + h0 + 1] = q1;
            }
        }
    }
}

__global__ __launch_bounds__(1024) void gat_blocksum_kernel(
    const int* __restrict__ count, int* __restrict__ bsum)
{
    __shared__ int ws[16];
    int tid = threadIdx.x, lane = tid & 63, wv = tid >> 6;
    int i = blockIdx.x * SCB + tid;
    int v = (i < NN) ? count[i] : 0;
    #pragma unroll
    for (int off = 32; off; off >>= 1) v += __shfl_down(v, off, 64);
    if (lane == 0) ws[wv] = v;
    __syncthreads();
    if (wv == 0) {
        int t = (lane < 16) ? ws[lane] : 0;
        #pragma unroll
        for (int off = 8; off; off >>= 1) t += __shfl_down(t, off, 64);
        if (lane == 0) bsum[blockIdx.x] = t;
    }
}

// 2-level scan; wave 1 computes this block's global offset from bsum inline
__global__ __launch_bounds__(1024) void gat_scan_kernel(
    const int* __restrict__ count, const int* __restrict__ bsum,
    int* __restrict__ rowptr, int* __restrict__ cursor)
{
    __shared__ int ws[16];
    __shared__ int boff_s;
    int tid = threadIdx.x, lane = tid & 63, wv = tid >> 6;
    int i = blockIdx.x * SCB + tid;
    int v = (i < NN) ? count[i] : 0;
    int incl = v;
    #pragma unroll
    for (int off = 1; off < 64; off <<= 1) {
        int t = __shfl_up(incl, off, 64);
        if (lane >= off) incl += t;
    }
    if (lane == 63) ws[wv] = incl;
    __syncthreads();
    if (wv == 0) {
        int t = (lane < 16) ? ws[lane] : 0;
        int winc = t;
        #pragma unroll
        for (int off = 1; off < 16; off <<= 1) {
            int u = __shfl_up(winc, off, 64);
            if (lane >= off) winc += u;
        }
        if (lane < 16) ws[lane] = winc - t;
    } else if (wv == 1) {
        // exclusive prefix of bsum over blocks < blockIdx.x (blockIdx.x <= 48 < 64)
        int t = (lane < blockIdx.x) ? bsum[lane] : 0;
        #pragma unroll
        for (int off = 32; off; off >>= 1) t += __shfl_down(t, off, 64);
        if (lane == 0) boff_s = t;
    }
    __syncthreads();
    int excl = boff_s + ws[wv] + incl - v;
    if (i < NN) { rowptr[i] = excl; cursor[i] = excl; }
    if (blockIdx.x == 0 && tid == 0) rowptr[NN] = EE;
}

__global__ __launch_bounds__(256) void gat_fill_kernel(
    const int* __restrict__ idx, int* __restrict__ cursor, int* __restrict__ col)
{
    int k = blockIdx.x * 256 + threadIdx.x;
    if (k >= EE) return;
    int d = idx[EE + k];
    int pos = atomicAdd(&cursor[d], 1);
    col[pos] = idx[k];
}

// one wave per dst node; lane owns channels (2*lane, 2*lane+1); head = lane>>4
__global__ __launch_bounds__(256) void gat_gather_kernel(
    const int* __restrict__ rowptr, const int* __restrict__ col,
    const float* __restrict__ a_src, const float* __restrict__ a_dst,
    const ushort* __restrict__ xpb, const float* __restrict__ skip,
    float* __restrict__ out)
{
    int wid = (blockIdx.x * 256 + threadIdx.x) >> 6;
    int lane = threadIdx.x & 63;
    if (wid >= NN) return;
    const int d = wid;
    const int h = lane >> 4;
    const int ch = lane * 2;
    const float ad = a_dst[(size_t)d * 4 + h];
    const int beg = rowptr[d], end = rowptr[d + 1];
    float2 sk = *reinterpret_cast<const float2*>(skip + (size_t)d * FD + ch);

    float accx = 0.f, accy = 0.f, asum = 0.f;
    int j = beg;
    for (; j + 4 <= end; j += 4) {
        int s0 = col[j], s1 = col[j + 1], s2 = col[j + 2], s3 = col[j + 3];
        float e0 = a_src[(size_t)s0 * 4 + h] + ad;
        float e1 = a_src[(size_t)s1 * 4 + h] + ad;
        float e2 = a_src[(size_t)s2 * 4 + h] + ad;
        float e3 = a_src[(size_t)s3 * 4 + h] + ad;
        ushort2 x0 = *reinterpret_cast<const ushort2*>(xpb + (size_t)s0 * FD + ch);
        ushort2 x1 = *reinterpret_cast<const ushort2*>(xpb + (size_t)s1 * FD + ch);
        ushort2 x2 = *reinterpret_cast<const ushort2*>(xpb + (size_t)s2 * FD + ch);
        ushort2 x3 = *reinterpret_cast<const ushort2*>(xpb + (size_t)s3 * FD + ch);
        e0 = e0 > 0.f ? e0 : NEG_SLOPE * e0;
        e1 = e1 > 0.f ? e1 : NEG_SLOPE * e1;
        e2 = e2 > 0.f ? e2 : NEG_SLOPE * e2;
        e3 = e3 > 0.f ? e3 : NEG_SLOPE * e3;
        float p0 = __expf(e0), p1 = __expf(e1), p2 = __expf(e2), p3 = __expf(e3);
        asum += (p0 + p1) + (p2 + p3);
        accx += p0 * b2f(x0.x) + p1 * b2f(x1.x) + p2 * b2f(x2.x) + p3 * b2f(x3.x);
        accy += p0 * b2f(x0.y) + p1 * b2f(x1.y) + p2 * b2f(x2.y) + p3 * b2f(x3.y);
    }
    for (; j < end; ++j) {
        int s = col[j];
        float e = a_src[(size_t)s * 4 + h] + ad;
        ushort2 xv = *reinterpret_cast<const ushort2*>(xpb + (size_t)s * FD + ch);
        e = e > 0.f ? e : NEG_SLOPE * e;
        float p = __expf(e);
        asum += p;
        accx += p * b2f(xv.x);
        accy += p * b2f(xv.y);
    }
    float inv = 1.f / (asum + 1e-16f);
    float r0 = sk.x + accx * inv;
    float r1 = sk.y + accy * inv;
    r0 = r0 > 0.f ? r0 : expm1f(r0);
    r1 = r1 > 0.f ? r1 : expm1f(r1);
    *reinterpret_cast<float2*>(out + (size_t)d * FD + ch) = make_float2(r0, r1);
}

extern "C" void kernel_launch(void* const* d_in, const int* in_sizes, int n_in,
                              void* d_out, int out_size, void* d_ws, size_t ws_size,
                              hipStream_t stream)
{
    const float* x       = (const float*)d_in[0];
    const int*   idx     = (const int*)d_in[1];
    const float* W       = (const float*)d_in[2];
    const float* att_src = (const float*)d_in[3];
    const float* att_dst = (const float*)d_in[4];
    const float* bias    = (const float*)d_in[5];
    const float* skip_W  = (const float*)d_in[6];
    const float* skip_b  = (const float*)d_in[7];
    float*       out     = (float*)d_out;

    float*  ws     = (float*)d_ws;
    float*  skip   = ws;                         // 6,400,000 f32
    float*  a_src  = ws + 6400000;               //   200,000 f32
    float*  a_dst  = ws + 6600000;               //   200,000 f32
    int*    count  = (int*)(ws + 6800000);       //    50,000 i32
    int*    rowptr = (int*)(ws + 6852000);       //    50,001 i32
    int*    cursor = (int*)(ws + 6904000);       //    50,000 i32
    int*    col    = (int*)(ws + 6956000);       //   800,000 i32
    int*    bsum   = (int*)(ws + 7800000);       //        49 i32
    ushort* xpb    = (ushort*)(ws + 7900000);    // 6,400,000 u16
    ushort* wb     = (ushort*)(ws + 11200000);   //    32,768 u16
    // total ~45 MB

    hipMemsetAsync(count, 0, (size_t)NN * sizeof(int), stream);

    gat_pre_kernel<<<NB_HIST + NB_CONVW, 256, 0, stream>>>(idx, count, W, skip_W, wb);

    gat_mfma_kernel<<<NN / 16, 256, 0, stream>>>(
        x, wb, att_src, att_dst, bias, skip_b, xpb, a_src, a_dst, skip);

    gat_blocksum_kernel<<<NB_SC, SCB, 0, stream>>>(count, bsum);
    gat_scan_kernel<<<NB_SC, SCB, 0, stream>>>(count, bsum, rowptr, cursor);
    gat_fill_kernel<<<(EE + 255) / 256, 256, 0, stream>>>(idx, cursor, col);

    gat_gather_kernel<<<(NN * 64) / 256, 256, 0, stream>>>(
        rowptr, col, a_src, a_dst, xpb, skip, out);
}

// Round 8
// 135.008 us; speedup vs baseline: 12.4561x; 1.3304x over previous
//
#include <hip/hip_runtime.h>
#include <hip/hip_bf16.h>

// GAT residual block: N=50000, IN=128, H=4, C=32 (H*C=128), E=800000.
// Inputs fp32 (edge_index int32): x, edge_index, W, att_src, att_dst, bias, skip_W, skip_b
// Output: float32 [N,128]
//
// 6 dispatches:
//  memset(count)
//  K1 pre:    blocks 0..3124: rank[k] = count[d]++ (atomic, rank store coalesced);
//             blocks 3125..3156: wb = bf16([W; skip_W])
//  K2 blocksum: per-1024-chunk sums of count
//  K3 scan:   2-level exclusive scan -> rowptr (block prefix of bsum inline, wave 1)
//  K4 mfma+fill (fused, independent halves):
//     blocks 0..3124:    per 16-row strip, 4 waves x 64 cols, mfma_f32_16x16x32_bf16.
//                        A-frags: fp32 x converted in-register. Waves 0,1 -> xpb (bf16)
//                        + a_src/a_dst logits; waves 2,3 -> skip + skip_b + bias.
//     blocks 3125..6249: col[rowptr[d] + rank[k]] = src   (no atomics)
//  K5 gather: one wave per dst (scalar d), unroll-4: acc += exp(e)*xpb[src], denom in
//             same pass; out = elu(skip + acc/denom).
// Segment-max skipped (softmax shift invariance, |e| <~ 6).

#define NN 50000
#define EE 800000
#define FD 128
#define NEG_SLOPE 0.2f

#define SCB 1024
#define NB_SC ((NN + SCB - 1) / SCB)   // 49
#define NB_HIST (EE / 256)             // 3125
#define NB_CONVW 32                    // 32768 elems / 4 / 256
#define NB_MFMA (NN / 16)              // 3125

typedef __attribute__((ext_vector_type(8))) short short8;   // 8 bf16 = 4 VGPR
typedef __attribute__((ext_vector_type(4))) float f32x4;

__device__ inline ushort f2b(float f) {
    __hip_bfloat16 h = __float2bfloat16(f);
    return *reinterpret_cast<ushort*>(&h);
}
__device__ inline float b2f(ushort u) {
    union { float f; unsigned int i; } c;
    c.i = ((unsigned int)u) << 16;
    return c.f;
}

// blocks [0, NB_HIST): histogram + rank capture; [NB_HIST, NB_HIST+NB_CONVW): W conv
__global__ __launch_bounds__(256) void gat_pre_kernel(
    const int* __restrict__ idx, int* __restrict__ count, int* __restrict__ rank,
    const float* __restrict__ W, const float* __restrict__ skip_W,
    ushort* __restrict__ wb)
{
    int b = blockIdx.x;
    if (b < NB_HIST) {
        int k = b * 256 + threadIdx.x;          // exact: 3125*256 = 800000
        int d = idx[EE + k];
        rank[k] = atomicAdd(&count[d], 1);
    } else {
        int i = ((b - NB_HIST) * 256 + threadIdx.x) * 4;   // < 32768
        int row = i >> 7;
        int colb = i & 127;
        const float* src = (row < 128) ? (W + row * FD + colb)
                                       : (skip_W + (row - 128) * FD + colb);
        float4 v = *reinterpret_cast<const float4*>(src);
        ushort4 o;
        o.x = f2b(v.x); o.y = f2b(v.y); o.z = f2b(v.z); o.w = f2b(v.w);
        *reinterpret_cast<ushort4*>(wb + i) = o;
    }
}

__global__ __launch_bounds__(1024) void gat_blocksum_kernel(
    const int* __restrict__ count, int* __restrict__ bsum)
{
    __shared__ int ws[16];
    int tid = threadIdx.x, lane = tid & 63, wv = tid >> 6;
    int i = blockIdx.x * SCB + tid;
    int v = (i < NN) ? count[i] : 0;
    #pragma unroll
    for (int off = 32; off; off >>= 1) v += __shfl_down(v, off, 64);
    if (lane == 0) ws[wv] = v;
    __syncthreads();
    if (wv == 0) {
        int t = (lane < 16) ? ws[lane] : 0;
        #pragma unroll
        for (int off = 8; off; off >>= 1) t += __shfl_down(t, off, 64);
        if (lane == 0) bsum[blockIdx.x] = t;
    }
}

// 2-level scan; wave 1 computes this block's global offset from bsum inline
__global__ __launch_bounds__(1024) void gat_scan_kernel(
    const int* __restrict__ count, const int* __restrict__ bsum,
    int* __restrict__ rowptr)
{
    __shared__ int ws[16];
    __shared__ int boff_s;
    int tid = threadIdx.x, lane = tid & 63, wv = tid >> 6;
    int i = blockIdx.x * SCB + tid;
    int v = (i < NN) ? count[i] : 0;
    int incl = v;
    #pragma unroll
    for (int off = 1; off < 64; off <<= 1) {
        int t = __shfl_up(incl, off, 64);
        if (lane >= off) incl += t;
    }
    if (lane == 63) ws[wv] = incl;
    __syncthreads();
    if (wv == 0) {
        int t = (lane < 16) ? ws[lane] : 0;
        int winc = t;
        #pragma unroll
        for (int off = 1; off < 16; off <<= 1) {
            int u = __shfl_up(winc, off, 64);
            if (lane >= off) winc += u;
        }
        if (lane < 16) ws[lane] = winc - t;
    } else if (wv == 1) {
        int t = (lane < blockIdx.x) ? bsum[lane] : 0;   // blockIdx.x <= 48 < 64
        #pragma unroll
        for (int off = 32; off; off >>= 1) t += __shfl_down(t, off, 64);
        if (lane == 0) boff_s = t;
    }
    __syncthreads();
    int excl = boff_s + ws[wv] + incl - v;
    if (i < NN) rowptr[i] = excl;
    if (blockIdx.x == 0 && tid == 0) rowptr[NN] = EE;
}

// fused: blocks [0, NB_MFMA) = MFMA strips; [NB_MFMA, NB_MFMA+NB_HIST) = CSR fill
__global__ __launch_bounds__(256) void gat_mfma_fill_kernel(
    const float* __restrict__ x, const ushort* __restrict__ wb,
    const float* __restrict__ att_src, const float* __restrict__ att_dst,
    const float* __restrict__ bias, const float* __restrict__ skip_b,
    ushort* __restrict__ xpb, float* __restrict__ a_src, float* __restrict__ a_dst,
    float* __restrict__ skip,
    const int* __restrict__ idx, const int* __restrict__ rank,
    const int* __restrict__ rowptr, int* __restrict__ col)
{
    if (blockIdx.x >= NB_MFMA) {
        // ---- fill half: no atomics ----
        int k = (blockIdx.x - NB_MFMA) * 256 + threadIdx.x;   // exact 800000
        int d = idx[EE + k];
        col[rowptr[d] + rank[k]] = idx[k];
        return;
    }

    // ---- MFMA half ----
    const int tid = threadIdx.x;
    const int w = tid >> 6;
    const int l = tid & 63;
    const int lrow = l & 15;
    const int lgrp = l >> 4;
    const int m0 = blockIdx.x * 16;
    const int is_skip = w >> 1;
    const int ncb = (w & 1) * 64;

    // B frags: wb row j = is_skip*128 + ncb + t*16 + lrow; k = kk*32 + lgrp*8 .. +8
    short8 bfrag[4][4];
    const ushort* wbase = wb + (size_t)(is_skip * 128 + ncb) * FD;
    #pragma unroll
    for (int t = 0; t < 4; ++t)
        #pragma unroll
        for (int kk = 0; kk < 4; ++kk)
            bfrag[t][kk] = *reinterpret_cast<const short8*>(
                wbase + (size_t)(t * 16 + lrow) * FD + kk * 32 + lgrp * 8);

    // A frags: fp32 x row m0+lrow, converted in-register
    short8 afrag[4];
    const float* xrow = x + (size_t)(m0 + lrow) * FD + lgrp * 8;
    #pragma unroll
    for (int kk = 0; kk < 4; ++kk) {
        float4 a0 = *reinterpret_cast<const float4*>(xrow + kk * 32);
        float4 a1 = *reinterpret_cast<const float4*>(xrow + kk * 32 + 4);
        short8 af;
        af[0] = f2b(a0.x); af[1] = f2b(a0.y); af[2] = f2b(a0.z); af[3] = f2b(a0.w);
        af[4] = f2b(a1.x); af[5] = f2b(a1.y); af[6] = f2b(a1.z); af[7] = f2b(a1.w);
        afrag[kk] = af;
    }

    f32x4 acc[4];
    #pragma unroll
    for (int t = 0; t < 4; ++t) acc[t] = (f32x4){0.f, 0.f, 0.f, 0.f};

    #pragma unroll
    for (int kk = 0; kk < 4; ++kk)
        #pragma unroll
        for (int t = 0; t < 4; ++t)
            acc[t] = __builtin_amdgcn_mfma_f32_16x16x32_bf16(
                afrag[kk], bfrag[t][kk], acc[t], 0, 0, 0);

    // C/D: element (row = 4*lgrp + r, col = lrow) of tile t; col_t = ncb + t*16 + lrow
    if (is_skip) {
        #pragma unroll
        for (int t = 0; t < 4; ++t) {
            int colt = ncb + t * 16 + lrow;
            float add = skip_b[colt] + bias[colt];
            #pragma unroll
            for (int r = 0; r < 4; ++r) {
                int row = m0 + lgrp * 4 + r;
                skip[(size_t)row * FD + colt] = acc[t][r] + add;
            }
        }
    } else {
        float as[4], ad[4];
        #pragma unroll
        for (int t = 0; t < 4; ++t) {
            int colt = ncb + t * 16 + lrow;
            as[t] = att_src[colt];
            ad[t] = att_dst[colt];
            #pragma unroll
            for (int r = 0; r < 4; ++r) {
                int row = m0 + lgrp * 4 + r;
                xpb[(size_t)row * FD + colt] = f2b(acc[t][r]);
            }
        }
        const int h0 = ncb >> 5;   // tiles 0,1 -> head h0; tiles 2,3 -> head h0+1
        #pragma unroll
        for (int r = 0; r < 4; ++r) {
            float p0 = acc[0][r] * as[0] + acc[1][r] * as[1];
            float p1 = acc[2][r] * as[2] + acc[3][r] * as[3];
            float q0 = acc[0][r] * ad[0] + acc[1][r] * ad[1];
            float q1 = acc[2][r] * ad[2] + acc[3][r] * ad[3];
            #pragma unroll
            for (int m = 1; m < 16; m <<= 1) {
                p0 += __shfl_xor(p0, m, 64);
                p1 += __shfl_xor(p1, m, 64);
                q0 += __shfl_xor(q0, m, 64);
                q1 += __shfl_xor(q1, m, 64);
            }
            if (lrow == 0) {
                int row = m0 + lgrp * 4 + r;
                a_src[(size_t)row * 4 + h0]     = p0;
                a_src[(size_t)row * 4 + h0 + 1] = p1;
                a_dst[(size_t)row * 4 + h0]     = q0;
                a_dst[(size_t)row * 4 + h0 + 1] = q1;
            }
        }
    }
}

// one wave per dst node (scalar d); lane owns channels (2*lane, 2*lane+1); head = lane>>4
__global__ __launch_bounds__(256) void gat_gather_kernel(
    const int* __restrict__ rowptr, const int* __restrict__ col,
    const float* __restrict__ a_src, const float* __restrict__ a_dst,
    const ushort* __restrict__ xpb, const float* __restrict__ skip,
    float* __restrict__ out)
{
    int wid = (blockIdx.x * 256 + threadIdx.x) >> 6;
    const int d = __builtin_amdgcn_readfirstlane(wid);   // wave-uniform -> SGPR
    int lane = threadIdx.x & 63;
    const int h = lane >> 4;
    const int ch = lane * 2;
    const float ad = a_dst[(size_t)d * 4 + h];
    const int beg = rowptr[d], end = rowptr[d + 1];
    float2 sk = *reinterpret_cast<const float2*>(skip + (size_t)d * FD + ch);

    float accx = 0.f, accy = 0.f, asum = 0.f;
    int j = beg;
    for (; j + 4 <= end; j += 4) {
        int s0 = col[j], s1 = col[j + 1], s2 = col[j + 2], s3 = col[j + 3];
        float e0 = a_src[(size_t)s0 * 4 + h] + ad;
        float e1 = a_src[(size_t)s1 * 4 + h] + ad;
        float e2 = a_src[(size_t)s2 * 4 + h] + ad;
        float e3 = a_src[(size_t)s3 * 4 + h] + ad;
        ushort2 x0 = *reinterpret_cast<const ushort2*>(xpb + (size_t)s0 * FD + ch);
        ushort2 x1 = *reinterpret_cast<const ushort2*>(xpb + (size_t)s1 * FD + ch);
        ushort2 x2 = *reinterpret_cast<const ushort2*>(xpb + (size_t)s2 * FD + ch);
        ushort2 x3 = *reinterpret_cast<const ushort2*>(xpb + (size_t)s3 * FD + ch);
        e0 = e0 > 0.f ? e0 : NEG_SLOPE * e0;
        e1 = e1 > 0.f ? e1 : NEG_SLOPE * e1;
        e2 = e2 > 0.f ? e2 : NEG_SLOPE * e2;
        e3 = e3 > 0.f ? e3 : NEG_SLOPE * e3;
        float p0 = __expf(e0), p1 = __expf(e1), p2 = __expf(e2), p3 = __expf(e3);
        asum += (p0 + p1) + (p2 + p3);
        accx += p0 * b2f(x0.x) + p1 * b2f(x1.x) + p2 * b2f(x2.x) + p3 * b2f(x3.x);
        accy += p0 * b2f(x0.y) + p1 * b2f(x1.y) + p2 * b2f(x2.y) + p3 * b2f(x3.y);
    }
    for (; j < end; ++j) {
        int s = col[j];
        float e = a_src[(size_t)s * 4 + h] + ad;
        ushort2 xv = *reinterpret_cast<const ushort2*>(xpb + (size_t)s * FD + ch);
        e = e > 0.f ? e : NEG_SLOPE * e;
        float p = __expf(e);
        asum += p;
        accx += p * b2f(xv.x);
        accy += p * b2f(xv.y);
    }
    float inv = 1.f / (asum + 1e-16f);
    float r0 = sk.x + accx * inv;
    float r1 = sk.y + accy * inv;
    r0 = r0 > 0.f ? r0 : expm1f(r0);
    r1 = r1 > 0.f ? r1 : expm1f(r1);
    *reinterpret_cast<float2*>(out + (size_t)d * FD + ch) = make_float2(r0, r1);
}

extern "C" void kernel_launch(void* const* d_in, const int* in_sizes, int n_in,
                              void* d_out, int out_size, void* d_ws, size_t ws_size,
                              hipStream_t stream)
{
    const float* x       = (const float*)d_in[0];
    const int*   idx     = (const int*)d_in[1];
    const float* W       = (const float*)d_in[2];
    const float* att_src = (const float*)d_in[3];
    const float* att_dst = (const float*)d_in[4];
    const float* bias    = (const float*)d_in[5];
    const float* skip_W  = (const float*)d_in[6];
    const float* skip_b  = (const float*)d_in[7];
    float*       out     = (float*)d_out;

    float*  ws     = (float*)d_ws;
    float*  skip   = ws;                         // 6,400,000 f32
    float*  a_src  = ws + 6400000;               //   200,000 f32
    float*  a_dst  = ws + 6600000;               //   200,000 f32
    int*    count  = (int*)(ws + 6800000);       //    50,000 i32
    int*    rowptr = (int*)(ws + 6852000);       //    50,001 i32
    int*    col    = (int*)(ws + 6956000);       //   800,000 i32
    int*    rank   = (int*)(ws + 7756000);       //   800,000 i32
    int*    bsum   = (int*)(ws + 8556000);       //        49 i32
    ushort* xpb    = (ushort*)(ws + 8600000);    // 6,400,000 u16
    ushort* wb     = (ushort*)(ws + 11900000);   //    32,768 u16
    // total ~48 MB

    hipMemsetAsync(count, 0, (size_t)NN * sizeof(int), stream);

    gat_pre_kernel<<<NB_HIST + NB_CONVW, 256, 0, stream>>>(idx, count, rank, W, skip_W, wb);

    gat_blocksum_kernel<<<NB_SC, SCB, 0, stream>>>(count, bsum);
    gat_scan_kernel<<<NB_SC, SCB, 0, stream>>>(count, bsum, rowptr);

    gat_mfma_fill_kernel<<<NB_MFMA + NB_HIST, 256, 0, stream>>>(
        x, wb, att_src, att_dst, bias, skip_b, xpb, a_src, a_dst, skip,
        idx, rank, rowptr, col);

    gat_gather_kernel<<<(NN * 64) / 256, 256, 0, stream>>>(
        rowptr, col, a_src, a_dst, xpb, skip, out);
}